// Round 4
// baseline (212.061 us; speedup 1.0000x reference)
//
#include <hip/hip_runtime.h>
#include <hip/hip_bf16.h>
#include <math.h>

#define B_ 2
#define N_ 2048
#define C_ 1024
#define H_ 16
#define G_ 4
#define D_ 64

using short8  = __attribute__((ext_vector_type(8))) short;
using float4v = __attribute__((ext_vector_type(4))) float;

__device__ __forceinline__ ushort f2bf(float f) {
    union { float f; unsigned u; } v; v.f = f;
    unsigned r = (v.u + 0x7FFF + ((v.u >> 16) & 1)) >> 16;  // RNE
    return (ushort)r;
}
__device__ __forceinline__ float bf2f(ushort u) {
    union { unsigned u; float f; } t; t.u = ((unsigned)u) << 16; return t.f;
}

// pack two f32 -> packed bf16x2 (gfx950 v_cvt_pk_bf16_f32 if available)
__device__ __forceinline__ unsigned pack_bf16(float a, float b) {
#if __has_builtin(__builtin_amdgcn_cvt_pk_bf16_f32)
    auto t = __builtin_amdgcn_cvt_pk_bf16_f32(a, b);
    unsigned r; __builtin_memcpy(&r, &t, 4); return r;
#else
    return (unsigned)f2bf(a) | ((unsigned)f2bf(b) << 16);
#endif
}

__device__ __forceinline__ float fexp2(float x) {
#if __has_builtin(__builtin_amdgcn_exp2f)
    return __builtin_amdgcn_exp2f(x);
#else
    return exp2f(x);
#endif
}

// ---------------------------------------------------------------------------
// x fp32 -> bf16
// ---------------------------------------------------------------------------
__global__ void convert_x(const float* __restrict__ x, ushort* __restrict__ xb) {
    int i = (blockIdx.x * 256 + threadIdx.x) * 4;
    float4 v = *(const float4*)(x + i);
    ushort4 o;
    o.x = f2bf(v.x); o.y = f2bf(v.y); o.z = f2bf(v.z); o.w = f2bf(v.w);
    *(ushort4*)(xb + i) = o;
}

// ---------------------------------------------------------------------------
// Transpose-convert: src [K][N] fp32 -> dst [N][K] bf16 (dst row stride = K)
// ---------------------------------------------------------------------------
__global__ void tconv(const float* __restrict__ src, ushort* __restrict__ dst,
                      int K, int N) {
    __shared__ float T[64][65];
    const int n0 = blockIdx.x * 64, k0 = blockIdx.y * 64;
    const int tid = threadIdx.x;
    #pragma unroll
    for (int s = 0; s < 16; ++s) {
        int idx = tid + s * 256; int r = idx >> 6, cc = idx & 63;
        T[r][cc] = src[(size_t)(k0 + r) * N + n0 + cc];
    }
    __syncthreads();
    #pragma unroll
    for (int s = 0; s < 16; ++s) {
        int idx = tid + s * 256; int r = idx >> 6, cc = idx & 63;
        dst[(size_t)(n0 + r) * K + k0 + cc] = f2bf(T[cc][r]);
    }
}

// ---------------------------------------------------------------------------
// m97-style bf16 MFMA GEMM: C[M][N] = A[M][K] @ Bt[N][K]^T.
// 128x128 tile, BK=32, 256 threads, global_load_lds width-16 staging,
// 2-barrier K-loop, 16 MFMA / wave / iter.
// ---------------------------------------------------------------------------
template <bool F32OUT>
__global__ __launch_bounds__(256) void gemm128(const ushort* __restrict__ A,
                                               const ushort* __restrict__ Bt,
                                               void* __restrict__ Cv,
                                               int M, int N, int K) {
    __shared__ __align__(16) ushort As[128 * 32];   // [row][k], 64 B rows
    __shared__ __align__(16) ushort Bs[128 * 32];

    const int tid = threadIdx.x, wave = tid >> 6, lane = tid & 63;
    const int g = lane >> 4, c = lane & 15;
    const int m0 = blockIdx.y * 128, n0 = blockIdx.x * 128;

    // staging source addresses: chunk t covers rows (wave*2+t)*16, 16B/lane
    const int srow = lane >> 2, schunk = (lane & 3) * 8;
    const ushort* pa0 = A  + (size_t)(m0 + (wave * 2 + 0) * 16 + srow) * K + schunk;
    const ushort* pa1 = A  + (size_t)(m0 + (wave * 2 + 1) * 16 + srow) * K + schunk;
    const ushort* pb0 = Bt + (size_t)(n0 + (wave * 2 + 0) * 16 + srow) * K + schunk;
    const ushort* pb1 = Bt + (size_t)(n0 + (wave * 2 + 1) * 16 + srow) * K + schunk;
    ushort* la0 = &As[(wave * 2 + 0) * 16 * 32];
    ushort* la1 = &As[(wave * 2 + 1) * 16 * 32];
    ushort* lb0 = &Bs[(wave * 2 + 0) * 16 * 32];
    ushort* lb1 = &Bs[(wave * 2 + 1) * 16 * 32];

    float4v acc[2][8];
    #pragma unroll
    for (int a = 0; a < 2; ++a)
        #pragma unroll
        for (int n = 0; n < 8; ++n) acc[a][n] = {0, 0, 0, 0};

    for (int k0 = 0; k0 < K; k0 += 32) {
        __builtin_amdgcn_global_load_lds(
            (const __attribute__((address_space(1))) void*)(pa0 + k0),
            (__attribute__((address_space(3))) void*)la0, 16, 0, 0);
        __builtin_amdgcn_global_load_lds(
            (const __attribute__((address_space(1))) void*)(pa1 + k0),
            (__attribute__((address_space(3))) void*)la1, 16, 0, 0);
        __builtin_amdgcn_global_load_lds(
            (const __attribute__((address_space(1))) void*)(pb0 + k0),
            (__attribute__((address_space(3))) void*)lb0, 16, 0, 0);
        __builtin_amdgcn_global_load_lds(
            (const __attribute__((address_space(1))) void*)(pb1 + k0),
            (__attribute__((address_space(3))) void*)lb1, 16, 0, 0);
        __syncthreads();   // drains vmcnt(0): staged data visible

        short8 af0 = *(const short8*)&As[(wave * 32 + c) * 32 + 8 * g];
        short8 af1 = *(const short8*)&As[(wave * 32 + 16 + c) * 32 + 8 * g];
        #pragma unroll
        for (int n = 0; n < 8; ++n) {
            short8 bfn = *(const short8*)&Bs[(n * 16 + c) * 32 + 8 * g];
            acc[0][n] = __builtin_amdgcn_mfma_f32_16x16x32_bf16(af0, bfn, acc[0][n], 0, 0, 0);
            acc[1][n] = __builtin_amdgcn_mfma_f32_16x16x32_bf16(af1, bfn, acc[1][n], 0, 0, 0);
        }
        __syncthreads();   // all reads done before next-iter staging overwrites
    }

    #pragma unroll
    for (int a = 0; a < 2; ++a)
        #pragma unroll
        for (int n = 0; n < 8; ++n)
            #pragma unroll
            for (int r = 0; r < 4; ++r) {
                int rowi = m0 + wave * 32 + a * 16 + 4 * g + r;
                int coli = n0 + n * 16 + c;
                if (F32OUT) ((float*)Cv)[(size_t)rowi * N + coli] = acc[a][n][r];
                else ((ushort*)Cv)[(size_t)rowi * N + coli] = (ushort)pack_bf16(acc[a][n][r], acc[a][n][r]);
            }
}

// ---------------------------------------------------------------------------
// qkvb [M][1536] bf16 -> Kt[b][j][d] bf16 (rope(sum_g k_g)),
// VtT[b][d][j'] bf16 (sum_g v_g), j' = key-permuted within 32-chunks.
// ---------------------------------------------------------------------------
__global__ void kv_reduce2(const ushort* __restrict__ qkvb,
                           ushort* __restrict__ Kt, ushort* __restrict__ VtT) {
    const int wid = threadIdx.x >> 6, d = threadIdx.x & 63;
    const int rowg = blockIdx.x * 4 + wid;          // b*N + n
    const int n = rowg & (N_ - 1), b = rowg >> 11;

    const ushort* base = qkvb + (size_t)rowg * 1536 + 1024;
    float ks = 0.f, vs = 0.f;
    #pragma unroll
    for (int g = 0; g < G_; ++g) {
        ks += bf2f(base[g * 64 + d]);
        vs += bf2f(base[256 + g * 64 + d]);
    }
    float partner = __shfl_xor(ks, 32, 64);
    float rh = (d < 32) ? -partner : partner;
    float ang = (float)n * __powf(10000.0f, -(float)(d & 31) * (1.0f / 32.0f));
    float sn, cs; __sincosf(ang, &sn, &cs);

    Kt[(size_t)rowg * 64 + d] = f2bf(ks * cs + rh * sn);
    int jp = (n & ~31) | (((n & 15) << 1) | ((n >> 4) & 1));
    VtT[((size_t)b * 64 + d) * N_ + jp] = f2bf(vs);
}

// ---------------------------------------------------------------------------
// Flash attention v3: 32 Q-rows/wave (128/block), rope-fused Q with
// log2e folded (p = exp2(s)), no-max softmax, hw-packed P, bf16 out.
// ---------------------------------------------------------------------------
#define KS 72
#define PS 40
#define QSCALE 0.18033688011112042f   // 0.125 * log2(e)

__global__ __launch_bounds__(256) void attn3(
        const ushort* __restrict__ qkvb, const ushort* __restrict__ Kt,
        const ushort* __restrict__ VtT, ushort* __restrict__ ao) {
    const int qt = blockIdx.x & 15;                 // N/128
    const int h  = (blockIdx.x >> 4) & 15;
    const int b  = blockIdx.x >> 8;
    const int tid = threadIdx.x, wave = tid >> 6, lane = tid & 63;
    const int g = lane >> 4, c = lane & 15;

    __shared__ __align__(16) ushort Ksh[64 * KS];
    __shared__ __align__(16) ushort Vsh[64 * KS];
    __shared__ __align__(16) ushort Psh[4][32 * PS];

    const int i0 = qt * 128 + wave * 32;
    // Q load + RoPE + scale (d<->d+32 partner is the raw0/raw1 register pair)
    short8 qf[2][2];
    #pragma unroll
    for (int a = 0; a < 2; ++a) {
        const int row = i0 + a * 16 + c;
        const ushort* qrow = qkvb + (size_t)(b * N_ + row) * 1536 + h * 64;
        short8 raw0 = *(const short8*)(qrow + 8 * g);
        short8 raw1 = *(const short8*)(qrow + 32 + 8 * g);
        #pragma unroll
        for (int i = 0; i < 8; ++i) {
            int dd = 8 * g + i;
            float f0 = bf2f((ushort)raw0[i]), f1 = bf2f((ushort)raw1[i]);
            float ang = (float)row * __powf(10000.0f, -(float)dd * (1.0f / 32.0f));
            float sn, cs; __sincosf(ang, &sn, &cs);
            qf[a][0][i] = (short)f2bf((f0 * cs - f1 * sn) * QSCALE);
            qf[a][1][i] = (short)f2bf((f1 * cs + f0 * sn) * QSCALE);
        }
    }

    float4v o[2][4];
    #pragma unroll
    for (int a = 0; a < 2; ++a)
        #pragma unroll
        for (int f = 0; f < 4; ++f) o[a][f] = {0, 0, 0, 0};
    float lr[2][4] = {};

    const ushort* Kb = Kt  + (size_t)b * N_ * 64;
    const ushort* Vb = VtT + (size_t)b * 64 * N_;
    const int s0r = tid >> 3,       s0q = tid & 7;
    const int s1r = 32 + (tid >> 3), s1q = tid & 7;

    short8 kr0 = *(const short8*)(Kb + (size_t)s0r * 64 + s0q * 8);
    short8 kr1 = *(const short8*)(Kb + (size_t)s1r * 64 + s1q * 8);
    short8 vr0 = *(const short8*)(Vb + (size_t)s0r * N_ + s0q * 8);
    short8 vr1 = *(const short8*)(Vb + (size_t)s1r * N_ + s1q * 8);

    for (int jt = 0; jt < N_; jt += 64) {
        __syncthreads();
        *(short8*)&Ksh[s0r * KS + s0q * 8] = kr0;
        *(short8*)&Ksh[s1r * KS + s1q * 8] = kr1;
        *(short8*)&Vsh[s0r * KS + s0q * 8] = vr0;
        *(short8*)&Vsh[s1r * KS + s1q * 8] = vr1;
        __syncthreads();
        int jtn = (jt + 64) & (N_ - 1);              // wraps harmlessly
        kr0 = *(const short8*)(Kb + (size_t)(jtn + s0r) * 64 + s0q * 8);
        kr1 = *(const short8*)(Kb + (size_t)(jtn + s1r) * 64 + s1q * 8);
        vr0 = *(const short8*)(Vb + (size_t)s0r * N_ + jtn + s0q * 8);
        vr1 = *(const short8*)(Vb + (size_t)s1r * N_ + jtn + s1q * 8);

        #pragma unroll
        for (int jj = 0; jj < 64; jj += 32) {
            // K frags shared across both row-groups
            short8 ka = *(const short8*)&Ksh[(jj + c) * KS + 8 * g];
            short8 kb = *(const short8*)&Ksh[(jj + c) * KS + 32 + 8 * g];
            short8 kc = *(const short8*)&Ksh[(jj + 16 + c) * KS + 8 * g];
            short8 kd = *(const short8*)&Ksh[(jj + 16 + c) * KS + 32 + 8 * g];
            float4v s[2][2];
            #pragma unroll
            for (int a = 0; a < 2; ++a) {
                s[a][0] = {0, 0, 0, 0}; s[a][1] = {0, 0, 0, 0};
                s[a][0] = __builtin_amdgcn_mfma_f32_16x16x32_bf16(qf[a][0], ka, s[a][0], 0, 0, 0);
                s[a][0] = __builtin_amdgcn_mfma_f32_16x16x32_bf16(qf[a][1], kb, s[a][0], 0, 0, 0);
                s[a][1] = __builtin_amdgcn_mfma_f32_16x16x32_bf16(qf[a][0], kc, s[a][1], 0, 0, 0);
                s[a][1] = __builtin_amdgcn_mfma_f32_16x16x32_bf16(qf[a][1], kd, s[a][1], 0, 0, 0);
            }
            // p = exp2(s); per-lane l accumulation; hw pack
            #pragma unroll
            for (int a = 0; a < 2; ++a)
                #pragma unroll
                for (int r = 0; r < 4; ++r) {
                    float p0 = fexp2(s[a][0][r]), p1 = fexp2(s[a][1][r]);
                    lr[a][r] += p0 + p1;
                    ((unsigned*)&Psh[wave][(a * 16 + 4 * g + r) * PS])[c] = pack_bf16(p0, p1);
                }
            short8 pf0 = *(const short8*)&Psh[wave][c * PS + 8 * g];
            short8 pf1 = *(const short8*)&Psh[wave][(16 + c) * PS + 8 * g];
            #pragma unroll
            for (int f = 0; f < 4; ++f) {
                short8 vf = *(const short8*)&Vsh[(16 * f + c) * KS + jj + 8 * g];
                o[0][f] = __builtin_amdgcn_mfma_f32_16x16x32_bf16(pf0, vf, o[0][f], 0, 0, 0);
                o[1][f] = __builtin_amdgcn_mfma_f32_16x16x32_bf16(pf1, vf, o[1][f], 0, 0, 0);
            }
        }
    }

    #pragma unroll
    for (int a = 0; a < 2; ++a)
        #pragma unroll
        for (int r = 0; r < 4; ++r) {
            float l = lr[a][r];
            #pragma unroll
            for (int m = 1; m < 16; m <<= 1) l += __shfl_xor(l, m, 64);
            float inv = 1.0f / l;
            size_t base = (size_t)(b * N_ + i0 + a * 16 + 4 * g + r) * C_ + h * 64 + c;
            ao[base]      = f2bf(o[a][0][r] * inv);
            ao[base + 16] = f2bf(o[a][1][r] * inv);
            ao[base + 32] = f2bf(o[a][2][r] * inv);
            ao[base + 48] = f2bf(o[a][3][r] * inv);
        }
}

// ---------------------------------------------------------------------------
extern "C" void kernel_launch(void* const* d_in, const int* in_sizes, int n_in,
                              void* d_out, int out_size, void* d_ws, size_t ws_size,
                              hipStream_t stream) {
    const float* x     = (const float*)d_in[0];
    const float* w_q   = (const float*)d_in[1];
    const float* w_kv  = (const float*)d_in[2];
    const float* w_out = (const float*)d_in[3];
    float* out = (float*)d_out;

    const int M = B_ * N_;                               // 4096
    ushort* xb    = (ushort*)d_ws;                       // 4096*1024
    ushort* wqkvT = xb    + (size_t)M * C_;              // 1536*1024
    ushort* woutT = wqkvT + (size_t)1536 * C_;           // 1024*1024
    ushort* qkvb  = woutT + (size_t)C_ * C_;             // 4096*1536
    ushort* Kt    = qkvb  + (size_t)M * 1536;            // 2*2048*64
    ushort* VtT   = Kt    + (size_t)B_ * N_ * D_;        // 2*64*2048
    ushort* ao    = xb;   // xb dead after qkv GEMM

    convert_x<<<(M * C_) / 1024, 256, 0, stream>>>(x, xb);
    tconv<<<dim3(16, 16), 256, 0, stream>>>(w_q,  wqkvT,                   C_, C_);
    tconv<<<dim3(8, 16),  256, 0, stream>>>(w_kv, wqkvT + (size_t)C_ * C_, C_, 2 * G_ * D_);
    tconv<<<dim3(16, 16), 256, 0, stream>>>(w_out, woutT,                  C_, C_);

    gemm128<false><<<dim3(1536 / 128, M / 128), 256, 0, stream>>>(xb, wqkvT, qkvb, M, 1536, C_);
    kv_reduce2<<<M / 4, 256, 0, stream>>>(qkvb, Kt, VtT);
    attn3<<<B_ * H_ * (N_ / 128), 256, 0, stream>>>(qkvb, Kt, VtT, ao);
    gemm128<true><<<dim3(C_ / 128, M / 128), 256, 0, stream>>>(ao, woutT, out, M, C_, C_);
}

// Round 5
// 200.526 us; speedup vs baseline: 1.0575x; 1.0575x over previous
//
#include <hip/hip_runtime.h>
#include <hip/hip_bf16.h>
#include <math.h>

#define B_ 2
#define N_ 2048
#define C_ 1024
#define H_ 16
#define G_ 4
#define D_ 64

using short8  = __attribute__((ext_vector_type(8))) short;
using float4v = __attribute__((ext_vector_type(4))) float;

__device__ __forceinline__ ushort f2bf(float f) {
    union { float f; unsigned u; } v; v.f = f;
    unsigned r = (v.u + 0x7FFF + ((v.u >> 16) & 1)) >> 16;  // RNE
    return (ushort)r;
}
__device__ __forceinline__ float bf2f(ushort u) {
    union { unsigned u; float f; } t; t.u = ((unsigned)u) << 16; return t.f;
}
__device__ __forceinline__ unsigned pack_bf16(float a, float b) {
#if __has_builtin(__builtin_amdgcn_cvt_pk_bf16_f32)
    auto t = __builtin_amdgcn_cvt_pk_bf16_f32(a, b);
    unsigned r; __builtin_memcpy(&r, &t, 4); return r;
#else
    return (unsigned)f2bf(a) | ((unsigned)f2bf(b) << 16);
#endif
}
__device__ __forceinline__ float fexp2(float x) {
#if __has_builtin(__builtin_amdgcn_exp2f)
    return __builtin_amdgcn_exp2f(x);
#else
    return exp2f(x);
#endif
}

// ---------------------------------------------------------------------------
// x fp32 -> bf16
// ---------------------------------------------------------------------------
__global__ void convert_x(const float* __restrict__ x, ushort* __restrict__ xb) {
    int i = (blockIdx.x * 256 + threadIdx.x) * 4;
    float4 v = *(const float4*)(x + i);
    ushort4 o;
    o.x = f2bf(v.x); o.y = f2bf(v.y); o.z = f2bf(v.z); o.w = f2bf(v.w);
    *(ushort4*)(xb + i) = o;
}

// ---------------------------------------------------------------------------
// Transpose-convert: src [K][N] fp32 -> dst [N][K] bf16
// ---------------------------------------------------------------------------
__global__ void tconv(const float* __restrict__ src, ushort* __restrict__ dst,
                      int K, int N) {
    __shared__ float T[64][65];
    const int n0 = blockIdx.x * 64, k0 = blockIdx.y * 64;
    const int tid = threadIdx.x;
    #pragma unroll
    for (int s = 0; s < 16; ++s) {
        int idx = tid + s * 256; int r = idx >> 6, cc = idx & 63;
        T[r][cc] = src[(size_t)(k0 + r) * N + n0 + cc];
    }
    __syncthreads();
    #pragma unroll
    for (int s = 0; s < 16; ++s) {
        int idx = tid + s * 256; int r = idx >> 6, cc = idx & 63;
        dst[(size_t)(n0 + r) * K + k0 + cc] = f2bf(T[cc][r]);
    }
}

// ---------------------------------------------------------------------------
// bf16 MFMA GEMM, 64x64 tile, BK=32, global_load_lds(16) staging,
// 2-barrier K-loop. C[M][N] = A[M][K] @ Bt[N][K]^T.
// ---------------------------------------------------------------------------
template <bool F32OUT>
__global__ __launch_bounds__(256) void gemm64(const ushort* __restrict__ A,
                                              const ushort* __restrict__ Bt,
                                              void* __restrict__ Cv,
                                              int M, int N, int K) {
    __shared__ __align__(16) ushort As[64 * 32];   // rows of 64 B (m97 layout)
    __shared__ __align__(16) ushort Bs[64 * 32];

    const int tid = threadIdx.x, wave = tid >> 6, lane = tid & 63;
    const int g = lane >> 4, c = lane & 15;
    const int wr = wave >> 1, wc = wave & 1;
    const int m0 = blockIdx.y * 64, n0 = blockIdx.x * 64;

    // staging: lane covers row wave*16 + (lane>>2), chunk (lane&3)*8
    const int srow = wave * 16 + (lane >> 2), schunk = (lane & 3) * 8;
    const ushort* pa = A  + (size_t)(m0 + srow) * K + schunk;
    const ushort* pb = Bt + (size_t)(n0 + srow) * K + schunk;
    ushort* ldsA = &As[wave * 16 * 32];
    ushort* ldsB = &Bs[wave * 16 * 32];

    float4v acc[2][2] = {{{0,0,0,0},{0,0,0,0}},{{0,0,0,0},{0,0,0,0}}};

    for (int k0 = 0; k0 < K; k0 += 32) {
        __builtin_amdgcn_global_load_lds(
            (const __attribute__((address_space(1))) void*)(pa + k0),
            (__attribute__((address_space(3))) void*)ldsA, 16, 0, 0);
        __builtin_amdgcn_global_load_lds(
            (const __attribute__((address_space(1))) void*)(pb + k0),
            (__attribute__((address_space(3))) void*)ldsB, 16, 0, 0);
        __syncthreads();

        short8 af0 = *(const short8*)&As[(wr * 32 + c) * 32 + 8 * g];
        short8 af1 = *(const short8*)&As[(wr * 32 + 16 + c) * 32 + 8 * g];
        short8 bf0 = *(const short8*)&Bs[(wc * 32 + c) * 32 + 8 * g];
        short8 bf1 = *(const short8*)&Bs[(wc * 32 + 16 + c) * 32 + 8 * g];
        acc[0][0] = __builtin_amdgcn_mfma_f32_16x16x32_bf16(af0, bf0, acc[0][0], 0, 0, 0);
        acc[0][1] = __builtin_amdgcn_mfma_f32_16x16x32_bf16(af0, bf1, acc[0][1], 0, 0, 0);
        acc[1][0] = __builtin_amdgcn_mfma_f32_16x16x32_bf16(af1, bf0, acc[1][0], 0, 0, 0);
        acc[1][1] = __builtin_amdgcn_mfma_f32_16x16x32_bf16(af1, bf1, acc[1][1], 0, 0, 0);
        __syncthreads();   // all reads done before next DMA overwrites
    }

    #pragma unroll
    for (int a = 0; a < 2; ++a)
        #pragma unroll
        for (int bb = 0; bb < 2; ++bb)
            #pragma unroll
            for (int r = 0; r < 4; ++r) {
                int rowi = m0 + wr * 32 + a * 16 + 4 * g + r;
                int coli = n0 + wc * 32 + bb * 16 + c;
                if (F32OUT) ((float*)Cv)[(size_t)rowi * N + coli] = acc[a][bb][r];
                else ((ushort*)Cv)[(size_t)rowi * N + coli] = f2bf(acc[a][bb][r]);
            }
}

// ---------------------------------------------------------------------------
// qkvb [M][1536] bf16 -> Kt[b][j][d] (rope(sum_g k_g)), VtT[b][d][j'] (sum_g v),
// j' = key-permuted within 32-chunks (matches attn P-pack order).
// ---------------------------------------------------------------------------
__global__ void kv_reduce2(const ushort* __restrict__ qkvb,
                           ushort* __restrict__ Kt, ushort* __restrict__ VtT) {
    const int wid = threadIdx.x >> 6, d = threadIdx.x & 63;
    const int rowg = blockIdx.x * 4 + wid;          // b*N + n
    const int n = rowg & (N_ - 1), b = rowg >> 11;

    const ushort* base = qkvb + (size_t)rowg * 1536 + 1024;
    float ks = 0.f, vs = 0.f;
    #pragma unroll
    for (int g = 0; g < G_; ++g) {
        ks += bf2f(base[g * 64 + d]);
        vs += bf2f(base[256 + g * 64 + d]);
    }
    float partner = __shfl_xor(ks, 32, 64);
    float rh = (d < 32) ? -partner : partner;
    float ang = (float)n * __powf(10000.0f, -(float)(d & 31) * (1.0f / 32.0f));
    float sn, cs; __sincosf(ang, &sn, &cs);

    Kt[(size_t)rowg * 64 + d] = f2bf(ks * cs + rh * sn);
    int jp = (n & ~31) | (((n & 15) << 1) | ((n >> 4) & 1));
    VtT[((size_t)b * 64 + d) * N_ + jp] = f2bf(vs);
}

// ---------------------------------------------------------------------------
// Flash attention v5: 4 waves x 64 Q-rows (256 rows/block), K-split x2.
// global_load_lds staging with XOR chunk swizzle; l via ones-MFMA;
// partials: o (bf16, unnormalized) + l (fp32) -> combine pass.
// ---------------------------------------------------------------------------
#define PS 40
#define QSCALE 0.18033688011112042f   // 0.125 * log2(e)

__global__ __launch_bounds__(256) void attn5(
        const ushort* __restrict__ qkvb, const ushort* __restrict__ Kt,
        const ushort* __restrict__ VtT,
        ushort* __restrict__ oP0, ushort* __restrict__ oP1,
        float* __restrict__ lP0, float* __restrict__ lP1) {
    const int s  = blockIdx.x & 1;
    const int qt = (blockIdx.x >> 1) & 7;
    const int h  = (blockIdx.x >> 4) & 15;
    const int b  = blockIdx.x >> 8;
    const int tid = threadIdx.x, wave = tid >> 6, lane = tid & 63;
    const int g = lane >> 4, c = lane & 15;

    __shared__ __align__(16) ushort Ksh[64 * 64];   // rows 128 B, XOR-swizzled chunks
    __shared__ __align__(16) ushort Vsh[64 * 64];
    __shared__ __align__(16) ushort Psh[4][64 * PS];

    ushort* oPs = s ? oP1 : oP0;
    float*  lPs = s ? lP1 : lP0;

    const int i0 = qt * 256 + wave * 64;
    // Q prologue: RoPE + scale, 4 row-groups (partner d<->d+32 = reg pair)
    short8 qf[4][2];
    #pragma unroll
    for (int a = 0; a < 4; ++a) {
        const int row = i0 + a * 16 + c;
        const ushort* qrow = qkvb + (size_t)(b * N_ + row) * 1536 + h * 64;
        short8 raw0 = *(const short8*)(qrow + 8 * g);
        short8 raw1 = *(const short8*)(qrow + 32 + 8 * g);
        #pragma unroll
        for (int i = 0; i < 8; ++i) {
            int dd = 8 * g + i;
            float f0 = bf2f((ushort)raw0[i]), f1 = bf2f((ushort)raw1[i]);
            float ang = (float)row * __powf(10000.0f, -(float)dd * (1.0f / 32.0f));
            float sn, cs; __sincosf(ang, &sn, &cs);
            qf[a][0][i] = (short)f2bf((f0 * cs - f1 * sn) * QSCALE);
            qf[a][1][i] = (short)f2bf((f1 * cs + f0 * sn) * QSCALE);
        }
    }

    const short8 ones = {(short)0x3F80, (short)0x3F80, (short)0x3F80, (short)0x3F80,
                         (short)0x3F80, (short)0x3F80, (short)0x3F80, (short)0x3F80};

    float4v o[4][4];
    float4v o4[4];
    #pragma unroll
    for (int a = 0; a < 4; ++a) {
        o4[a] = {0, 0, 0, 0};
        #pragma unroll
        for (int f = 0; f < 4; ++f) o[a][f] = {0, 0, 0, 0};
    }

    const ushort* Kb = Kt  + (size_t)b * N_ * 64;
    const ushort* Vb = VtT + (size_t)b * 64 * N_;
    const int lr8 = lane >> 3, lq8 = lane & 7;
    const int swz = (lq8 ^ lr8) * 8;                 // XOR chunk swizzle
    const int j0 = s * (N_ / 2);

    for (int jt = j0; jt < j0 + N_ / 2; jt += 64) {
        __syncthreads();   // prev-tile LDS reads complete
        #pragma unroll
        for (int t = 0; t < 2; ++t) {
            const int row8 = wave * 16 + t * 8;      // 8 rows per wave-instr
            __builtin_amdgcn_global_load_lds(
                (const __attribute__((address_space(1))) void*)
                    (Kb + (size_t)(jt + row8 + lr8) * 64 + swz),
                (__attribute__((address_space(3))) void*)&Ksh[row8 * 64], 16, 0, 0);
            __builtin_amdgcn_global_load_lds(
                (const __attribute__((address_space(1))) void*)
                    (Vb + (size_t)(row8 + lr8) * N_ + jt + swz),
                (__attribute__((address_space(3))) void*)&Vsh[row8 * 64], 16, 0, 0);
        }
        __syncthreads();   // DMA drained

        #pragma unroll
        for (int jj = 0; jj < 64; jj += 32) {
            // ---- scores: s[a][t] over keys jj+16t+c
            float4v sc[4][2];
            #pragma unroll
            for (int t = 0; t < 2; ++t) {
                const int R = jj + 16 * t + c;
                short8 ka = *(const short8*)&Ksh[R * 64 + ((g ^ (c & 7)) * 8)];
                short8 kb = *(const short8*)&Ksh[R * 64 + (((g ^ 4) ^ (c & 7)) * 8)];
                #pragma unroll
                for (int a = 0; a < 4; ++a) {
                    if (t == 0) { sc[a][0] = {0,0,0,0}; sc[a][1] = {0,0,0,0}; }
                    sc[a][t] = __builtin_amdgcn_mfma_f32_16x16x32_bf16(qf[a][0], ka, sc[a][t], 0, 0, 0);
                    sc[a][t] = __builtin_amdgcn_mfma_f32_16x16x32_bf16(qf[a][1], kb, sc[a][t], 0, 0, 0);
                }
            }
            // ---- p = exp2(s), packed write (key jj+c -> lo, jj+16+c -> hi)
            #pragma unroll
            for (int a = 0; a < 4; ++a)
                #pragma unroll
                for (int r = 0; r < 4; ++r) {
                    float p0 = fexp2(sc[a][0][r]), p1 = fexp2(sc[a][1][r]);
                    ((unsigned*)&Psh[wave][(a * 16 + 4 * g + r) * PS])[c] = pack_bf16(p0, p1);
                }
            // ---- PV + l (ones column)
            const int vb = (jj >> 3);                // 0 or 4: chunk base
            #pragma unroll
            for (int a = 0; a < 4; ++a) {
                short8 pf = *(const short8*)&Psh[wave][(a * 16 + c) * PS + 8 * g];
                #pragma unroll
                for (int f = 0; f < 4; ++f) {
                    const int R = 16 * f + c;
                    short8 vf = *(const short8*)&Vsh[R * 64 + (((g ^ vb) ^ (c & 7)) * 8)];
                    o[a][f] = __builtin_amdgcn_mfma_f32_16x16x32_bf16(pf, vf, o[a][f], 0, 0, 0);
                }
                o4[a] = __builtin_amdgcn_mfma_f32_16x16x32_bf16(pf, ones, o4[a], 0, 0, 0);
            }
        }
    }

    // epilogue: unnormalized bf16 o + fp32 l partials
    #pragma unroll
    for (int a = 0; a < 4; ++a)
        #pragma unroll
        for (int r = 0; r < 4; ++r) {
            const int row = i0 + a * 16 + 4 * g + r;
            if (c == 0) lPs[(size_t)(b * N_ + row) * 16 + h] = o4[a][r];
            size_t base = (size_t)(b * N_ + row) * 1024 + h * 64 + c;
            oPs[base]      = f2bf(o[a][0][r]);
            oPs[base + 16] = f2bf(o[a][1][r]);
            oPs[base + 32] = f2bf(o[a][2][r]);
            oPs[base + 48] = f2bf(o[a][3][r]);
        }
}

// ---------------------------------------------------------------------------
// Combine: ao = (oP0 + oP1) / (lP0 + lP1), bf16 out (in-place over oP0 ok)
// ---------------------------------------------------------------------------
__global__ void combine(const ushort* __restrict__ oP0, const ushort* __restrict__ oP1,
                        const float* __restrict__ lP0, const float* __restrict__ lP1,
                        ushort* __restrict__ ao) {
    const int e = (blockIdx.x * 256 + threadIdx.x) * 4;
    const int row = e >> 10, hh = (e >> 6) & 15;
    const float inv = 1.0f / (lP0[row * 16 + hh] + lP1[row * 16 + hh]);
    ushort4 a = *(const ushort4*)(oP0 + e);
    ushort4 b = *(const ushort4*)(oP1 + e);
    ushort4 r;
    r.x = f2bf((bf2f(a.x) + bf2f(b.x)) * inv);
    r.y = f2bf((bf2f(a.y) + bf2f(b.y)) * inv);
    r.z = f2bf((bf2f(a.z) + bf2f(b.z)) * inv);
    r.w = f2bf((bf2f(a.w) + bf2f(b.w)) * inv);
    *(ushort4*)(ao + e) = r;
}

// ---------------------------------------------------------------------------
extern "C" void kernel_launch(void* const* d_in, const int* in_sizes, int n_in,
                              void* d_out, int out_size, void* d_ws, size_t ws_size,
                              hipStream_t stream) {
    const float* x     = (const float*)d_in[0];
    const float* w_q   = (const float*)d_in[1];
    const float* w_kv  = (const float*)d_in[2];
    const float* w_out = (const float*)d_in[3];
    float* out = (float*)d_out;

    const int M = B_ * N_;                               // 4096
    ushort* xb    = (ushort*)d_ws;                       // 4096*1024  (-> oP0 -> ao)
    ushort* wqkvT = xb    + (size_t)M * C_;              // 1536*1024
    ushort* woutT = wqkvT + (size_t)1536 * C_;           // 1024*1024
    ushort* qkvb  = woutT + (size_t)C_ * C_;             // 4096*1536
    ushort* Kt    = qkvb  + (size_t)M * 1536;            // 2*2048*64
    ushort* VtT   = Kt    + (size_t)B_ * N_ * D_;        // 2*64*2048
    ushort* oP1   = VtT   + (size_t)B_ * D_ * N_;        // 4096*1024 bf16 partial
    float*  lP0   = (float*)(oP1 + (size_t)M * C_);      // 4096*16 fp32
    float*  lP1   = lP0 + (size_t)M * H_;
    ushort* oP0   = xb;   // xb dead after qkv GEMM
    ushort* ao    = xb;   // combine writes in-place over oP0

    convert_x<<<(M * C_) / 1024, 256, 0, stream>>>(x, xb);
    tconv<<<dim3(16, 16), 256, 0, stream>>>(w_q,  wqkvT,                   C_, C_);
    tconv<<<dim3(8, 16),  256, 0, stream>>>(w_kv, wqkvT + (size_t)C_ * C_, C_, 2 * G_ * D_);
    tconv<<<dim3(16, 16), 256, 0, stream>>>(w_out, woutT,                  C_, C_);

    gemm64<false><<<dim3(1536 / 64, M / 64), 256, 0, stream>>>(xb, wqkvT, qkvb, M, 1536, C_);
    kv_reduce2<<<M / 4, 256, 0, stream>>>(qkvb, Kt, VtT);
    attn5<<<B_ * H_ * (N_ / 256) * 2, 256, 0, stream>>>(qkvb, Kt, VtT, oP0, oP1, lP0, lP1);
    combine<<<(M * C_) / 1024, 256, 0, stream>>>(oP0, oP1, lP0, lP1, ao);
    gemm64<true><<<dim3(C_ / 64, M / 64), 256, 0, stream>>>(ao, woutT, out, M, C_, C_);
}